// Round 13
// baseline (27.594 us; speedup 1.0000x reference)
//
#include <hip/hip_runtime.h>
#include <math.h>

typedef __attribute__((ext_vector_type(8))) _Float16 f16x8;
typedef __attribute__((ext_vector_type(4))) float f32x4;

#define TSTEPS 23
#define ROWS 128

// ws byte offsets
#define WSB_B1 0        // [64 n][168 k] f16 combined table *256 (21504 B)
#define WSB_W2 21504    // [64 n][72 k] f16 rw2 transposed (9216 B)
#define WSB_Z  30720    // [64][64] f32 RAW gate logit LUT (16384 B)

// ---- precompute: Z spread over 64 blocks (f64 combine 4x wider), 512 thr ----
__global__ __launch_bounds__(512) void pre_all(
    const float* __restrict__ embed, const float* __restrict__ gw1,
    const float* __restrict__ gb1, const float* __restrict__ gw2,
    const float* __restrict__ gb2, const float* __restrict__ rw1,
    const float* __restrict__ rb1, const float* __restrict__ rw2,
    char* __restrict__ wsc)
{
    __shared__ float sEmb[66 * 64];   // 16896 B
    __shared__ float sW[128 * 64];    // 32768 B
    __shared__ float sV[64 * 33];     // 8448 B
    __shared__ float sU[32];
    __shared__ float sG[65];          // gb1[0:32], gw2[32:64], gb2[64]
    __shared__ float sRb1[64];
    __shared__ double sP[512];        // f64 partials

    const int tid = threadIdx.x;
    const int blk = blockIdx.x;

    if (blk < 64) {
        // ---- Z row c = blk, fully in-block ----
        {
            const float4* es = (const float4*)embed;
            float4* ed = (float4*)sEmb;
            for (int i = tid; i < 1024; i += 512) ed[i] = es[i];
            const float4* gs = (const float4*)gw1;       // [128][32] = 1024 f4
            float4* gd = (float4*)sW;
            for (int i = tid; i < 1024; i += 512) gd[i] = gs[i];
            if (tid < 32) { sG[tid] = gb1[tid]; sG[32 + tid] = gw2[tid]; }
            if (tid == 64) sG[64] = gb2[0];
        }
        __syncthreads();
        // v: s = tid>>3 (er reg-cached), 4 consecutive j — k-ascending fma,
        // bitwise identical per-output chain to prior rounds
        {
            const int s = tid >> 3, j0 = (tid & 7) * 4;
            float4 er[16];
            const float4* erp = (const float4*)(sEmb + s * 64);
            #pragma unroll
            for (int q = 0; q < 16; ++q) er[q] = erp[q];
            float a0 = 0.f, a1 = 0.f, a2 = 0.f, a3 = 0.f;
            #pragma unroll
            for (int k = 0; k < 64; ++k) {
                const float ek = ((const float*)er)[k];
                const float4 w0 = *(const float4*)&sW[(64 + k) * 32 + j0];
                a0 = fmaf(ek, w0.x, a0); a1 = fmaf(ek, w0.y, a1);
                a2 = fmaf(ek, w0.z, a2); a3 = fmaf(ek, w0.w, a3);
            }
            float* vd = sV + s * 33 + j0;
            vd[0] = a0; vd[1] = a1; vd[2] = a2; vd[3] = a3;
        }
        // u: 32 outputs for this c-row (bitwise identical chain)
        if (tid < 32) {
            const int j = tid;
            float acc = 0.f;
            const float* er = sEmb + blk * 64;
            #pragma unroll
            for (int k = 0; k < 64; ++k)
                acc = fmaf(er[k], sW[k * 32 + j], acc);
            sU[j] = acc;
        }
        __syncthreads();
        // f64 combine: 8 threads per s (4 j each), f64 tree reduce
        {
            const int s = tid >> 3;
            const int j0 = (tid & 7) * 4;
            double p = 0.0;
            #pragma unroll
            for (int j = j0; j < j0 + 4; ++j) {
                const double a = (double)sU[j] + (double)sV[s * 33 + j] + (double)sG[j];
                if (a > 0.0) p += a * (double)sG[32 + j];
            }
            sP[tid] = p;
        }
        __syncthreads();
        if (tid < 64) {
            const double* pp = sP + tid * 8;
            const double z = (double)sG[64] +
                (((pp[0] + pp[1]) + (pp[2] + pp[3])) + ((pp[4] + pp[5]) + (pp[6] + pp[7])));
            ((float*)(wsc + WSB_Z))[blk * 64 + tid] = (float)z;
        }
    } else if (blk < 81) {
        // ---- B1 combined table: 8320 outputs, 1/thread, er reg-cached ----
        {
            const float4* es = (const float4*)embed;
            float4* ed = (float4*)sEmb;
            for (int i = tid; i < 1056; i += 512) ed[i] = es[i];
            const float4* rs = (const float4*)rw1;       // [128][64]
            float4* rd = (float4*)sW;
            for (int i = tid; i < 2048; i += 512) rd[i] = rs[i];
            if (tid < 64) sRb1[tid] = rb1[tid];
        }
        __syncthreads();
        const int e = (blk - 64) * 512 + tid;
        if (e < 8320) {
            const int n = e & 63, k = e >> 6;            // k < 130
            const int trow = (k < 64) ? k : (k - 64);
            const int ofs = (k < 64) ? 64 : 0;
            float4 er[16];
            const float4* erp = (const float4*)(sEmb + trow * 64);
            #pragma unroll
            for (int q = 0; q < 16; ++q) er[q] = erp[q];
            float acc = (k < 64) ? 0.f : sRb1[n];
            #pragma unroll
            for (int m = 0; m < 64; ++m)
                acc = fmaf(((const float*)er)[m], sW[(ofs + m) * 64 + n], acc);
            acc *= (k < 64) ? (0.125f * 256.f) : 256.f;
            ((_Float16*)(wsc + WSB_B1))[n * 168 + k] = (_Float16)acc;
        }
    } else {
        // ---- W2 transpose + B1 k-pads ----
        _Float16* w2t = (_Float16*)(wsc + WSB_W2);
        for (int e = tid; e < 4096; e += 512) {
            const int n = e & 63, j = e >> 6;
            w2t[n * 72 + j] = (_Float16)rw2[j * 64 + n];
        }
        _Float16* b1 = (_Float16*)(wsc + WSB_B1);
        for (int e = tid; e < 2432; e += 512) {          // k in [130,168)
            const int n = e / 38, k = 130 + (e - n * 38);
            b1[n * 168 + k] = (_Float16)0.f;
        }
    }
}

// ---- A-window builders (unchanged) ----
__device__ __forceinline__ f16x8 build_slot_win(const unsigned* s, const unsigned* hb, int ko)
{
    unsigned w0 = 0, w1 = 0, w2 = 0, w3 = 0;
    #pragma unroll
    for (int i = 0; i < 8; ++i) {
        const unsigned d = s[i] - (unsigned)ko;
        const unsigned val = (d < 8u) ? (hb[i] << ((d & 1u) * 16)) : 0u;
        const unsigned q = d >> 1;
        w0 |= (q == 0u) ? val : 0u;
        w1 |= (q == 1u) ? val : 0u;
        w2 |= (q == 2u) ? val : 0u;
        w3 |= (q == 3u) ? val : 0u;
    }
    union { unsigned u[4]; f16x8 v; } r;
    r.u[0] = w0; r.u[1] = w1; r.u[2] = w2; r.u[3] = w3;
    return r.v;
}

__device__ __forceinline__ f16x8 build_q_win(int kq, int ko)
{
    const unsigned d = (unsigned)(kq - ko);
    const unsigned val = (d < 8u) ? (0x3C00u << ((d & 1u) * 16)) : 0u;
    const unsigned q = d >> 1;
    union { unsigned u[4]; f16x8 v; } r;
    r.u[0] = (q == 0u) ? val : 0u;
    r.u[1] = (q == 1u) ? val : 0u;
    r.u[2] = (q == 2u) ? val : 0u;
    r.u[3] = (q == 3u) ? val : 0u;
    return r.v;
}

// LDS byte offsets (68096 B arena) — sOut f32[128][68] overlays [0, 34816)
#define L_Z    0        // f32[64][65] padded 16640
#define L_B1   16640    // f16[64][168] 21504
#define L_W2   38144    // f16[64][72]   9216
#define L_H    47360    // f16[128][72] 18432
#define L_ROW  65792    // uint4[128]    2048
#define L_RB2  67840    // f32[64]        256

__global__ __launch_bounds__(512) void sm_main(
    const int* __restrict__ seqs, const int* __restrict__ qtok,
    const float* __restrict__ rb2, const char* __restrict__ wsc,
    float* __restrict__ out)
{
    __shared__ __align__(16) char smem[68096];
    float*    sZ   = (float*)(smem + L_Z);
    _Float16* sB1  = (_Float16*)(smem + L_B1);
    _Float16* sW2  = (_Float16*)(smem + L_W2);
    _Float16* sH   = (_Float16*)(smem + L_H);
    uint4*    sRow = (uint4*)(smem + L_ROW);
    float*    sRb2 = (float*)(smem + L_RB2);

    const int tid = threadIdx.x;
    const int base = blockIdx.x * ROWS;

    unsigned pk[6];
    int qt = 0;
    if (tid < ROWS) {
        const int4* sq = (const int4*)(seqs + (size_t)(base + tid) * 24);
        #pragma unroll
        for (int i = 0; i < 6; ++i) {
            const int4 w4 = sq[i];
            pk[i] = (unsigned)w4.x | ((unsigned)w4.y << 8) |
                    ((unsigned)w4.z << 16) | ((unsigned)w4.w << 24);
        }
        qt = qtok[base + tid];
    }

    {
        const float* zsrc = (const float*)(wsc + WSB_Z);
        #pragma unroll
        for (int i = 0; i < 8; ++i) {
            const int e = tid + i * 512;
            sZ[(e >> 6) * 65 + (e & 63)] = zsrc[e];
        }
        if (tid < 64) sRb2[tid] = rb2[tid];
    }
    __syncthreads();

    if (tid < ROWS) {
        unsigned lo = pk[0], hi = pk[1];
        #pragma unroll
        for (int t = 8; t < TSTEPS; ++t) {
            const int c = (int)((pk[t >> 2] >> ((t & 3) * 8)) & 255u);
            const float* zr = sZ + c * 65;
            float b = zr[lo & 63]; int am = 0; float z;
            z = zr[(lo >> 8) & 63];  if (z > b) { b = z; am = 1; }
            z = zr[(lo >> 16) & 63]; if (z > b) { b = z; am = 2; }
            z = zr[lo >> 24];        if (z > b) { b = z; am = 3; }
            z = zr[hi & 63];         if (z > b) { b = z; am = 4; }
            z = zr[(hi >> 8) & 63];  if (z > b) { b = z; am = 5; }
            z = zr[(hi >> 16) & 63]; if (z > b) { b = z; am = 6; }
            z = zr[hi >> 24];        if (z > b) { b = z; am = 7; }
            const unsigned cb = (unsigned)c;
            if (am < 4) { const int sh = am * 8; lo = (lo & ~(255u << sh)) | (cb << sh); }
            else        { const int sh = am * 8 - 32; hi = (hi & ~(255u << sh)) | (cb << sh); }
        }
        int t_[8] = { (int)(lo & 63), (int)((lo >> 8) & 63), (int)((lo >> 16) & 63), (int)(lo >> 24),
                      (int)(hi & 63), (int)((hi >> 8) & 63), (int)((hi >> 16) & 63), (int)(hi >> 24) };
        int tot[8] = {1, 1, 1, 1, 1, 1, 1, 1};
        #pragma unroll
        for (int i = 0; i < 8; ++i)
            #pragma unroll
            for (int j = i + 1; j < 8; ++j) {
                const int eq = (t_[i] == t_[j]);
                tot[i] += eq; tot[j] += eq;
            }
        unsigned tp = 0;
        #pragma unroll
        for (int i = 0; i < 8; ++i) tp |= (unsigned)tot[i] << (4 * i);
        sRow[tid] = make_uint4(lo & 0x3F3F3F3Fu, hi & 0x3F3F3F3Fu, tp, (unsigned)qt);
    } else {
        const int t2 = tid - 128;
        const float4* b1s = (const float4*)(wsc + WSB_B1);
        float4* b1d = (float4*)sB1;
        for (int i = t2; i < 1344; i += 384) b1d[i] = b1s[i];
        const float4* w2s = (const float4*)(wsc + WSB_W2);
        float4* w2d = (float4*)sW2;
        for (int i = t2; i < 576; i += 384) w2d[i] = w2s[i];
    }
    __syncthreads();

    const int lane = tid & 63;
    const int w = tid >> 6;
    const int c16 = lane & 15, g = lane >> 4;
    const int arow = w * 16 + c16;

    unsigned sl[8], hb[8];
    int kq;
    {
        const uint4 ri = sRow[arow];
        sl[0] = ri.x & 63u; sl[1] = (ri.x >> 8) & 63u;
        sl[2] = (ri.x >> 16) & 63u; sl[3] = ri.x >> 24;
        sl[4] = ri.y & 63u; sl[5] = (ri.y >> 8) & 63u;
        sl[6] = (ri.y >> 16) & 63u; sl[7] = ri.y >> 24;
        #pragma unroll
        for (int i = 0; i < 8; ++i) {
            const unsigned tot = (ri.z >> (4 * i)) & 15u;
            union { _Float16 h; unsigned short b; } cv;
            cv.h = (_Float16)(float)tot;
            hb[i] = (unsigned)cv.b;
        }
        kq = 64 + (int)ri.w;
    }

    f32x4 a0 = {0.f, 0.f, 0.f, 0.f}, a1 = a0, a2 = a0, a3 = a0;
    #pragma unroll
    for (int ks = 0; ks < 5; ++ks) {
        const int ko = ks * 32 + g * 8;
        const f16x8 af = (ks < 2) ? build_slot_win(sl, hb, ko) : build_q_win(kq, ko);
        const f16x8 b0 = *(const f16x8*)&sB1[(c16) * 168 + ko];
        const f16x8 b1 = *(const f16x8*)&sB1[(16 + c16) * 168 + ko];
        const f16x8 b2 = *(const f16x8*)&sB1[(32 + c16) * 168 + ko];
        const f16x8 b3 = *(const f16x8*)&sB1[(48 + c16) * 168 + ko];
        a0 = __builtin_amdgcn_mfma_f32_16x16x32_f16(af, b0, a0, 0, 0, 0);
        a1 = __builtin_amdgcn_mfma_f32_16x16x32_f16(af, b1, a1, 0, 0, 0);
        a2 = __builtin_amdgcn_mfma_f32_16x16x32_f16(af, b2, a2, 0, 0, 0);
        a3 = __builtin_amdgcn_mfma_f32_16x16x32_f16(af, b3, a3, 0, 0, 0);
    }
    {
        const int rbase = w * 16 + g * 4;
        #pragma unroll
        for (int j = 0; j < 4; ++j) {
            _Float16* hr = sH + (rbase + j) * 72;
            const float v0 = a0[j], v1 = a1[j], v2 = a2[j], v3 = a3[j];
            hr[c16]      = (_Float16)(v0 > 0.f ? v0 : 0.f);
            hr[16 + c16] = (_Float16)(v1 > 0.f ? v1 : 0.f);
            hr[32 + c16] = (_Float16)(v2 > 0.f ? v2 : 0.f);
            hr[48 + c16] = (_Float16)(v3 > 0.f ? v3 : 0.f);
        }
    }
    __syncthreads();

    f32x4 d0 = {0.f, 0.f, 0.f, 0.f}, d1 = d0, d2 = d0, d3 = d0;
    #pragma unroll
    for (int ks = 0; ks < 2; ++ks) {
        const int ko = ks * 32 + g * 8;
        const f16x8 af = *(const f16x8*)&sH[arow * 72 + ko];
        const f16x8 b0 = *(const f16x8*)&sW2[(c16) * 72 + ko];
        const f16x8 b1 = *(const f16x8*)&sW2[(16 + c16) * 72 + ko];
        const f16x8 b2 = *(const f16x8*)&sW2[(32 + c16) * 72 + ko];
        const f16x8 b3 = *(const f16x8*)&sW2[(48 + c16) * 72 + ko];
        d0 = __builtin_amdgcn_mfma_f32_16x16x32_f16(af, b0, d0, 0, 0, 0);
        d1 = __builtin_amdgcn_mfma_f32_16x16x32_f16(af, b1, d1, 0, 0, 0);
        d2 = __builtin_amdgcn_mfma_f32_16x16x32_f16(af, b2, d2, 0, 0, 0);
        d3 = __builtin_amdgcn_mfma_f32_16x16x32_f16(af, b3, d3, 0, 0, 0);
    }
    float* sOut = (float*)(void*)smem;      // overlays dead sZ/sB1
    {
        const int rbase = w * 16 + g * 4;
        #pragma unroll
        for (int j = 0; j < 4; ++j) {
            float* orow = sOut + (rbase + j) * 68;
            orow[c16]      = d0[j] * (1.f / 256.f) + sRb2[c16];
            orow[16 + c16] = d1[j] * (1.f / 256.f) + sRb2[16 + c16];
            orow[32 + c16] = d2[j] * (1.f / 256.f) + sRb2[32 + c16];
            orow[48 + c16] = d3[j] * (1.f / 256.f) + sRb2[48 + c16];
        }
    }
    __syncthreads();

    #pragma unroll
    for (int r2 = 0; r2 < 4; ++r2) {
        const int idx = r2 * 512 + tid;
        const int row = idx >> 4, c4 = idx & 15;
        *(float4*)(out + (size_t)(base + row) * 64 + c4 * 4) =
            *(const float4*)&sOut[row * 68 + c4 * 4];
    }
}

extern "C" void kernel_launch(void* const* d_in, const int* in_sizes, int n_in,
                              void* d_out, int out_size, void* d_ws, size_t ws_size,
                              hipStream_t stream)
{
    const int* seqs    = (const int*)d_in[0];
    const int* qtok    = (const int*)d_in[1];
    const float* embed = (const float*)d_in[2];
    const float* gw1   = (const float*)d_in[3];
    const float* gb1   = (const float*)d_in[4];
    const float* gw2   = (const float*)d_in[5];
    const float* gb2   = (const float*)d_in[6];
    const float* rw1   = (const float*)d_in[7];
    const float* rb1   = (const float*)d_in[8];
    const float* rw2   = (const float*)d_in[9];
    const float* rb2   = (const float*)d_in[10];
    char* wsc  = (char*)d_ws;
    float* out = (float*)d_out;
    const int B = in_sizes[1];

    pre_all<<<82, 512, 0, stream>>>(embed, gw1, gb1, gw2, gb2, rw1, rb1, rw2, wsc);
    // CALIBRATION: sm_main launched twice (identical, deterministic output).
    // dur_delta vs single-launch isolates sm_main's true marginal cost.
    sm_main<<<B / ROWS, 512, 0, stream>>>(seqs, qtok, rb2, wsc, out);
    sm_main<<<B / ROWS, 512, 0, stream>>>(seqs, qtok, rb2, wsc, out);
}

// Round 14
// 23.142 us; speedup vs baseline: 1.1924x; 1.1924x over previous
//
#include <hip/hip_runtime.h>
#include <math.h>

typedef __attribute__((ext_vector_type(8))) _Float16 f16x8;
typedef __attribute__((ext_vector_type(4))) float f32x4;

#define TSTEPS 23
#define ROWS 128

// ws byte offsets
#define WSB_B1 0        // [64 n][168 k] f16 combined table *256 (21504 B)
#define WSB_W2 21504    // [64 n][72 k] f16 rw2 transposed (9216 B)
#define WSB_Z  30720    // [64][64] f32 RAW gate logit LUT (16384 B)

// ---- precompute: Z blocks use LDS-broadcast er (no register array) ----
__global__ __launch_bounds__(512) void pre_all(
    const float* __restrict__ embed, const float* __restrict__ gw1,
    const float* __restrict__ gb1, const float* __restrict__ gw2,
    const float* __restrict__ gb2, const float* __restrict__ rw1,
    const float* __restrict__ rb1, const float* __restrict__ rw2,
    char* __restrict__ wsc)
{
    __shared__ float sEmb[66 * 64];   // 16896 B
    __shared__ float sW[128 * 64];    // 32768 B
    __shared__ float sV[64 * 33];     // 8448 B
    __shared__ float sU[32];
    __shared__ float sG[65];          // gb1[0:32], gw2[32:64], gb2[64]
    __shared__ float sRb1[64];
    __shared__ double sP[512];        // f64 partials

    const int tid = threadIdx.x;
    const int blk = blockIdx.x;

    if (blk < 64) {
        // ---- Z row c = blk, fully in-block ----
        {
            const float4* es = (const float4*)embed;
            float4* ed = (float4*)sEmb;
            for (int i = tid; i < 1024; i += 512) ed[i] = es[i];
            const float4* gs = (const float4*)gw1;       // [128][32] = 1024 f4
            float4* gd = (float4*)sW;
            for (int i = tid; i < 1024; i += 512) gd[i] = gs[i];
            if (tid < 32) { sG[tid] = gb1[tid]; sG[32 + tid] = gw2[tid]; }
            if (tid == 64) sG[64] = gb2[0];
        }
        __syncthreads();
        // v: s = tid>>3, 4 consecutive j. ek from LDS broadcast (no reg array).
        // fmaf chain k-ascending — bitwise identical to prior rounds.
        {
            const int s = tid >> 3, j0 = (tid & 7) * 4;
            const float* er = sEmb + s * 64;
            float a0 = 0.f, a1 = 0.f, a2 = 0.f, a3 = 0.f;
            #pragma unroll
            for (int k = 0; k < 64; ++k) {
                const float ek = er[k];
                const float4 w0 = *(const float4*)&sW[(64 + k) * 32 + j0];
                a0 = fmaf(ek, w0.x, a0); a1 = fmaf(ek, w0.y, a1);
                a2 = fmaf(ek, w0.z, a2); a3 = fmaf(ek, w0.w, a3);
            }
            float* vd = sV + s * 33 + j0;
            vd[0] = a0; vd[1] = a1; vd[2] = a2; vd[3] = a3;
        }
        // u: 32 outputs for this c-row (scalar LDS reads, identical chain)
        if (tid < 32) {
            const int j = tid;
            float acc = 0.f;
            const float* er = sEmb + blk * 64;
            #pragma unroll
            for (int k = 0; k < 64; ++k)
                acc = fmaf(er[k], sW[k * 32 + j], acc);
            sU[j] = acc;
        }
        __syncthreads();
        // f64 combine: 8 threads per s (4 j each), f64 tree reduce (== R13)
        {
            const int s = tid >> 3;
            const int j0 = (tid & 7) * 4;
            double p = 0.0;
            #pragma unroll
            for (int j = j0; j < j0 + 4; ++j) {
                const double a = (double)sU[j] + (double)sV[s * 33 + j] + (double)sG[j];
                if (a > 0.0) p += a * (double)sG[32 + j];
            }
            sP[tid] = p;
        }
        __syncthreads();
        if (tid < 64) {
            const double* pp = sP + tid * 8;
            const double z = (double)sG[64] +
                (((pp[0] + pp[1]) + (pp[2] + pp[3])) + ((pp[4] + pp[5]) + (pp[6] + pp[7])));
            ((float*)(wsc + WSB_Z))[blk * 64 + tid] = (float)z;
        }
    } else if (blk < 81) {
        // ---- B1 combined table: 8320 outputs, 1/thread, er reg-cached ----
        {
            const float4* es = (const float4*)embed;
            float4* ed = (float4*)sEmb;
            for (int i = tid; i < 1056; i += 512) ed[i] = es[i];
            const float4* rs = (const float4*)rw1;       // [128][64]
            float4* rd = (float4*)sW;
            for (int i = tid; i < 2048; i += 512) rd[i] = rs[i];
            if (tid < 64) sRb1[tid] = rb1[tid];
        }
        __syncthreads();
        const int e = (blk - 64) * 512 + tid;
        if (e < 8320) {
            const int n = e & 63, k = e >> 6;            // k < 130
            const int trow = (k < 64) ? k : (k - 64);
            const int ofs = (k < 64) ? 64 : 0;
            float4 er[16];
            const float4* erp = (const float4*)(sEmb + trow * 64);
            #pragma unroll
            for (int q = 0; q < 16; ++q) er[q] = erp[q];
            float acc = (k < 64) ? 0.f : sRb1[n];
            #pragma unroll
            for (int m = 0; m < 64; ++m)
                acc = fmaf(((const float*)er)[m], sW[(ofs + m) * 64 + n], acc);
            acc *= (k < 64) ? (0.125f * 256.f) : 256.f;
            ((_Float16*)(wsc + WSB_B1))[n * 168 + k] = (_Float16)acc;
        }
    } else {
        // ---- W2 transpose + B1 k-pads ----
        _Float16* w2t = (_Float16*)(wsc + WSB_W2);
        for (int e = tid; e < 4096; e += 512) {
            const int n = e & 63, j = e >> 6;
            w2t[n * 72 + j] = (_Float16)rw2[j * 64 + n];
        }
        _Float16* b1 = (_Float16*)(wsc + WSB_B1);
        for (int e = tid; e < 2432; e += 512) {          // k in [130,168)
            const int n = e / 38, k = 130 + (e - n * 38);
            b1[n * 168 + k] = (_Float16)0.f;
        }
    }
}

// ---- A-window builders (unchanged) ----
__device__ __forceinline__ f16x8 build_slot_win(const unsigned* s, const unsigned* hb, int ko)
{
    unsigned w0 = 0, w1 = 0, w2 = 0, w3 = 0;
    #pragma unroll
    for (int i = 0; i < 8; ++i) {
        const unsigned d = s[i] - (unsigned)ko;
        const unsigned val = (d < 8u) ? (hb[i] << ((d & 1u) * 16)) : 0u;
        const unsigned q = d >> 1;
        w0 |= (q == 0u) ? val : 0u;
        w1 |= (q == 1u) ? val : 0u;
        w2 |= (q == 2u) ? val : 0u;
        w3 |= (q == 3u) ? val : 0u;
    }
    union { unsigned u[4]; f16x8 v; } r;
    r.u[0] = w0; r.u[1] = w1; r.u[2] = w2; r.u[3] = w3;
    return r.v;
}

__device__ __forceinline__ f16x8 build_q_win(int kq, int ko)
{
    const unsigned d = (unsigned)(kq - ko);
    const unsigned val = (d < 8u) ? (0x3C00u << ((d & 1u) * 16)) : 0u;
    const unsigned q = d >> 1;
    union { unsigned u[4]; f16x8 v; } r;
    r.u[0] = (q == 0u) ? val : 0u;
    r.u[1] = (q == 1u) ? val : 0u;
    r.u[2] = (q == 2u) ? val : 0u;
    r.u[3] = (q == 3u) ? val : 0u;
    return r.v;
}

// LDS byte offsets (68096 B arena) — sOut f32[128][68] overlays [0, 34816)
#define L_Z    0        // f32[64][65] padded 16640
#define L_B1   16640    // f16[64][168] 21504
#define L_W2   38144    // f16[64][72]   9216
#define L_H    47360    // f16[128][72] 18432
#define L_ROW  65792    // uint4[128]    2048
#define L_RB2  67840    // f32[64]        256

__global__ __launch_bounds__(512) void sm_main(
    const int* __restrict__ seqs, const int* __restrict__ qtok,
    const float* __restrict__ rb2, const char* __restrict__ wsc,
    float* __restrict__ out)
{
    __shared__ __align__(16) char smem[68096];
    float*    sZ   = (float*)(smem + L_Z);
    _Float16* sB1  = (_Float16*)(smem + L_B1);
    _Float16* sW2  = (_Float16*)(smem + L_W2);
    _Float16* sH   = (_Float16*)(smem + L_H);
    uint4*    sRow = (uint4*)(smem + L_ROW);
    float*    sRb2 = (float*)(smem + L_RB2);

    const int tid = threadIdx.x;
    const int base = blockIdx.x * ROWS;

    unsigned pk[6];
    int qt = 0;
    if (tid < ROWS) {
        const int4* sq = (const int4*)(seqs + (size_t)(base + tid) * 24);
        #pragma unroll
        for (int i = 0; i < 6; ++i) {
            const int4 w4 = sq[i];
            pk[i] = (unsigned)w4.x | ((unsigned)w4.y << 8) |
                    ((unsigned)w4.z << 16) | ((unsigned)w4.w << 24);
        }
        qt = qtok[base + tid];
    }

    {
        const float* zsrc = (const float*)(wsc + WSB_Z);
        #pragma unroll
        for (int i = 0; i < 8; ++i) {
            const int e = tid + i * 512;
            sZ[(e >> 6) * 65 + (e & 63)] = zsrc[e];
        }
        if (tid < 64) sRb2[tid] = rb2[tid];
    }
    __syncthreads();

    if (tid < ROWS) {
        unsigned lo = pk[0], hi = pk[1];
        #pragma unroll
        for (int t = 8; t < TSTEPS; ++t) {
            const int c = (int)((pk[t >> 2] >> ((t & 3) * 8)) & 255u);
            const float* zr = sZ + c * 65;
            float b = zr[lo & 63]; int am = 0; float z;
            z = zr[(lo >> 8) & 63];  if (z > b) { b = z; am = 1; }
            z = zr[(lo >> 16) & 63]; if (z > b) { b = z; am = 2; }
            z = zr[lo >> 24];        if (z > b) { b = z; am = 3; }
            z = zr[hi & 63];         if (z > b) { b = z; am = 4; }
            z = zr[(hi >> 8) & 63];  if (z > b) { b = z; am = 5; }
            z = zr[(hi >> 16) & 63]; if (z > b) { b = z; am = 6; }
            z = zr[hi >> 24];        if (z > b) { b = z; am = 7; }
            const unsigned cb = (unsigned)c;
            if (am < 4) { const int sh = am * 8; lo = (lo & ~(255u << sh)) | (cb << sh); }
            else        { const int sh = am * 8 - 32; hi = (hi & ~(255u << sh)) | (cb << sh); }
        }
        int t_[8] = { (int)(lo & 63), (int)((lo >> 8) & 63), (int)((lo >> 16) & 63), (int)(lo >> 24),
                      (int)(hi & 63), (int)((hi >> 8) & 63), (int)((hi >> 16) & 63), (int)(hi >> 24) };
        int tot[8] = {1, 1, 1, 1, 1, 1, 1, 1};
        #pragma unroll
        for (int i = 0; i < 8; ++i)
            #pragma unroll
            for (int j = i + 1; j < 8; ++j) {
                const int eq = (t_[i] == t_[j]);
                tot[i] += eq; tot[j] += eq;
            }
        unsigned tp = 0;
        #pragma unroll
        for (int i = 0; i < 8; ++i) tp |= (unsigned)tot[i] << (4 * i);
        sRow[tid] = make_uint4(lo & 0x3F3F3F3Fu, hi & 0x3F3F3F3Fu, tp, (unsigned)qt);
    } else {
        const int t2 = tid - 128;
        const float4* b1s = (const float4*)(wsc + WSB_B1);
        float4* b1d = (float4*)sB1;
        for (int i = t2; i < 1344; i += 384) b1d[i] = b1s[i];
        const float4* w2s = (const float4*)(wsc + WSB_W2);
        float4* w2d = (float4*)sW2;
        for (int i = t2; i < 576; i += 384) w2d[i] = w2s[i];
    }
    __syncthreads();

    const int lane = tid & 63;
    const int w = tid >> 6;
    const int c16 = lane & 15, g = lane >> 4;
    const int arow = w * 16 + c16;

    unsigned sl[8], hb[8];
    int kq;
    {
        const uint4 ri = sRow[arow];
        sl[0] = ri.x & 63u; sl[1] = (ri.x >> 8) & 63u;
        sl[2] = (ri.x >> 16) & 63u; sl[3] = ri.x >> 24;
        sl[4] = ri.y & 63u; sl[5] = (ri.y >> 8) & 63u;
        sl[6] = (ri.y >> 16) & 63u; sl[7] = ri.y >> 24;
        #pragma unroll
        for (int i = 0; i < 8; ++i) {
            const unsigned tot = (ri.z >> (4 * i)) & 15u;
            union { _Float16 h; unsigned short b; } cv;
            cv.h = (_Float16)(float)tot;
            hb[i] = (unsigned)cv.b;
        }
        kq = 64 + (int)ri.w;
    }

    f32x4 a0 = {0.f, 0.f, 0.f, 0.f}, a1 = a0, a2 = a0, a3 = a0;
    #pragma unroll
    for (int ks = 0; ks < 5; ++ks) {
        const int ko = ks * 32 + g * 8;
        const f16x8 af = (ks < 2) ? build_slot_win(sl, hb, ko) : build_q_win(kq, ko);
        const f16x8 b0 = *(const f16x8*)&sB1[(c16) * 168 + ko];
        const f16x8 b1 = *(const f16x8*)&sB1[(16 + c16) * 168 + ko];
        const f16x8 b2 = *(const f16x8*)&sB1[(32 + c16) * 168 + ko];
        const f16x8 b3 = *(const f16x8*)&sB1[(48 + c16) * 168 + ko];
        a0 = __builtin_amdgcn_mfma_f32_16x16x32_f16(af, b0, a0, 0, 0, 0);
        a1 = __builtin_amdgcn_mfma_f32_16x16x32_f16(af, b1, a1, 0, 0, 0);
        a2 = __builtin_amdgcn_mfma_f32_16x16x32_f16(af, b2, a2, 0, 0, 0);
        a3 = __builtin_amdgcn_mfma_f32_16x16x32_f16(af, b3, a3, 0, 0, 0);
    }
    {
        const int rbase = w * 16 + g * 4;
        #pragma unroll
        for (int j = 0; j < 4; ++j) {
            _Float16* hr = sH + (rbase + j) * 72;
            const float v0 = a0[j], v1 = a1[j], v2 = a2[j], v3 = a3[j];
            hr[c16]      = (_Float16)(v0 > 0.f ? v0 : 0.f);
            hr[16 + c16] = (_Float16)(v1 > 0.f ? v1 : 0.f);
            hr[32 + c16] = (_Float16)(v2 > 0.f ? v2 : 0.f);
            hr[48 + c16] = (_Float16)(v3 > 0.f ? v3 : 0.f);
        }
    }
    __syncthreads();

    f32x4 d0 = {0.f, 0.f, 0.f, 0.f}, d1 = d0, d2 = d0, d3 = d0;
    #pragma unroll
    for (int ks = 0; ks < 2; ++ks) {
        const int ko = ks * 32 + g * 8;
        const f16x8 af = *(const f16x8*)&sH[arow * 72 + ko];
        const f16x8 b0 = *(const f16x8*)&sW2[(c16) * 72 + ko];
        const f16x8 b1 = *(const f16x8*)&sW2[(16 + c16) * 72 + ko];
        const f16x8 b2 = *(const f16x8*)&sW2[(32 + c16) * 72 + ko];
        const f16x8 b3 = *(const f16x8*)&sW2[(48 + c16) * 72 + ko];
        d0 = __builtin_amdgcn_mfma_f32_16x16x32_f16(af, b0, d0, 0, 0, 0);
        d1 = __builtin_amdgcn_mfma_f32_16x16x32_f16(af, b1, d1, 0, 0, 0);
        d2 = __builtin_amdgcn_mfma_f32_16x16x32_f16(af, b2, d2, 0, 0, 0);
        d3 = __builtin_amdgcn_mfma_f32_16x16x32_f16(af, b3, d3, 0, 0, 0);
    }
    float* sOut = (float*)(void*)smem;      // overlays dead sZ/sB1
    {
        const int rbase = w * 16 + g * 4;
        #pragma unroll
        for (int j = 0; j < 4; ++j) {
            float* orow = sOut + (rbase + j) * 68;
            orow[c16]      = d0[j] * (1.f / 256.f) + sRb2[c16];
            orow[16 + c16] = d1[j] * (1.f / 256.f) + sRb2[16 + c16];
            orow[32 + c16] = d2[j] * (1.f / 256.f) + sRb2[32 + c16];
            orow[48 + c16] = d3[j] * (1.f / 256.f) + sRb2[48 + c16];
        }
    }
    __syncthreads();

    #pragma unroll
    for (int r2 = 0; r2 < 4; ++r2) {
        const int idx = r2 * 512 + tid;
        const int row = idx >> 4, c4 = idx & 15;
        *(float4*)(out + (size_t)(base + row) * 64 + c4 * 4) =
            *(const float4*)&sOut[row * 68 + c4 * 4];
    }
}

extern "C" void kernel_launch(void* const* d_in, const int* in_sizes, int n_in,
                              void* d_out, int out_size, void* d_ws, size_t ws_size,
                              hipStream_t stream)
{
    const int* seqs    = (const int*)d_in[0];
    const int* qtok    = (const int*)d_in[1];
    const float* embed = (const float*)d_in[2];
    const float* gw1   = (const float*)d_in[3];
    const float* gb1   = (const float*)d_in[4];
    const float* gw2   = (const float*)d_in[5];
    const float* gb2   = (const float*)d_in[6];
    const float* rw1   = (const float*)d_in[7];
    const float* rb1   = (const float*)d_in[8];
    const float* rw2   = (const float*)d_in[9];
    const float* rb2   = (const float*)d_in[10];
    char* wsc  = (char*)d_ws;
    float* out = (float*)d_out;
    const int B = in_sizes[1];

    pre_all<<<82, 512, 0, stream>>>(embed, gw1, gb1, gw2, gb2, rw1, rb1, rw2, wsc);
    // PROBE: grid=64 re-runs ONLY the Z blocks (rewrites identical bytes,
    // deterministic). dur - 19.7 isolates the Z-path wall + one boundary.
    pre_all<<<64, 512, 0, stream>>>(embed, gw1, gb1, gw2, gb2, rw1, rb1, rw2, wsc);
    sm_main<<<B / ROWS, 512, 0, stream>>>(seqs, qtok, rb2, wsc, out);
}

// Round 15
// 22.718 us; speedup vs baseline: 1.2146x; 1.0187x over previous
//
#include <hip/hip_runtime.h>
#include <math.h>

typedef __attribute__((ext_vector_type(8))) _Float16 f16x8;
typedef __attribute__((ext_vector_type(4))) float f32x4;

#define TSTEPS 23
#define ROWS 64
#define BT 256

// ws byte offsets
#define WSB_B1 0        // [64 n][168 k] f16 combined table *256 (21504 B)
#define WSB_W2 21504    // [64 n][72 k] f16 rw2 transposed (9216 B)
#define WSB_Z  30720    // [64][64] f32 RAW gate logit LUT (16384 B)

// ---- precompute: VERBATIM R14 (Z LDS-broadcast, 82 blocks) ----
__global__ __launch_bounds__(512) void pre_all(
    const float* __restrict__ embed, const float* __restrict__ gw1,
    const float* __restrict__ gb1, const float* __restrict__ gw2,
    const float* __restrict__ gb2, const float* __restrict__ rw1,
    const float* __restrict__ rb1, const float* __restrict__ rw2,
    char* __restrict__ wsc)
{
    __shared__ float sEmb[66 * 64];
    __shared__ float sW[128 * 64];
    __shared__ float sV[64 * 33];
    __shared__ float sU[32];
    __shared__ float sG[65];
    __shared__ float sRb1[64];
    __shared__ double sP[512];

    const int tid = threadIdx.x;
    const int blk = blockIdx.x;

    if (blk < 64) {
        {
            const float4* es = (const float4*)embed;
            float4* ed = (float4*)sEmb;
            for (int i = tid; i < 1024; i += 512) ed[i] = es[i];
            const float4* gs = (const float4*)gw1;
            float4* gd = (float4*)sW;
            for (int i = tid; i < 1024; i += 512) gd[i] = gs[i];
            if (tid < 32) { sG[tid] = gb1[tid]; sG[32 + tid] = gw2[tid]; }
            if (tid == 64) sG[64] = gb2[0];
        }
        __syncthreads();
        {
            const int s = tid >> 3, j0 = (tid & 7) * 4;
            const float* er = sEmb + s * 64;
            float a0 = 0.f, a1 = 0.f, a2 = 0.f, a3 = 0.f;
            #pragma unroll
            for (int k = 0; k < 64; ++k) {
                const float ek = er[k];
                const float4 w0 = *(const float4*)&sW[(64 + k) * 32 + j0];
                a0 = fmaf(ek, w0.x, a0); a1 = fmaf(ek, w0.y, a1);
                a2 = fmaf(ek, w0.z, a2); a3 = fmaf(ek, w0.w, a3);
            }
            float* vd = sV + s * 33 + j0;
            vd[0] = a0; vd[1] = a1; vd[2] = a2; vd[3] = a3;
        }
        if (tid < 32) {
            const int j = tid;
            float acc = 0.f;
            const float* er = sEmb + blk * 64;
            #pragma unroll
            for (int k = 0; k < 64; ++k)
                acc = fmaf(er[k], sW[k * 32 + j], acc);
            sU[j] = acc;
        }
        __syncthreads();
        {
            const int s = tid >> 3;
            const int j0 = (tid & 7) * 4;
            double p = 0.0;
            #pragma unroll
            for (int j = j0; j < j0 + 4; ++j) {
                const double a = (double)sU[j] + (double)sV[s * 33 + j] + (double)sG[j];
                if (a > 0.0) p += a * (double)sG[32 + j];
            }
            sP[tid] = p;
        }
        __syncthreads();
        if (tid < 64) {
            const double* pp = sP + tid * 8;
            const double z = (double)sG[64] +
                (((pp[0] + pp[1]) + (pp[2] + pp[3])) + ((pp[4] + pp[5]) + (pp[6] + pp[7])));
            ((float*)(wsc + WSB_Z))[blk * 64 + tid] = (float)z;
        }
    } else if (blk < 81) {
        {
            const float4* es = (const float4*)embed;
            float4* ed = (float4*)sEmb;
            for (int i = tid; i < 1056; i += 512) ed[i] = es[i];
            const float4* rs = (const float4*)rw1;
            float4* rd = (float4*)sW;
            for (int i = tid; i < 2048; i += 512) rd[i] = rs[i];
            if (tid < 64) sRb1[tid] = rb1[tid];
        }
        __syncthreads();
        const int e = (blk - 64) * 512 + tid;
        if (e < 8320) {
            const int n = e & 63, k = e >> 6;
            const int trow = (k < 64) ? k : (k - 64);
            const int ofs = (k < 64) ? 64 : 0;
            float4 er[16];
            const float4* erp = (const float4*)(sEmb + trow * 64);
            #pragma unroll
            for (int q = 0; q < 16; ++q) er[q] = erp[q];
            float acc = (k < 64) ? 0.f : sRb1[n];
            #pragma unroll
            for (int m = 0; m < 64; ++m)
                acc = fmaf(((const float*)er)[m], sW[(ofs + m) * 64 + n], acc);
            acc *= (k < 64) ? (0.125f * 256.f) : 256.f;
            ((_Float16*)(wsc + WSB_B1))[n * 168 + k] = (_Float16)acc;
        }
    } else {
        _Float16* w2t = (_Float16*)(wsc + WSB_W2);
        for (int e = tid; e < 4096; e += 512) {
            const int n = e & 63, j = e >> 6;
            w2t[n * 72 + j] = (_Float16)rw2[j * 64 + n];
        }
        _Float16* b1 = (_Float16*)(wsc + WSB_B1);
        for (int e = tid; e < 2432; e += 512) {
            const int n = e / 38, k = 130 + (e - n * 38);
            b1[n * 168 + k] = (_Float16)0.f;
        }
    }
}

// ---- A-window builders (unchanged) ----
__device__ __forceinline__ f16x8 build_slot_win(const unsigned* s, const unsigned* hb, int ko)
{
    unsigned w0 = 0, w1 = 0, w2 = 0, w3 = 0;
    #pragma unroll
    for (int i = 0; i < 8; ++i) {
        const unsigned d = s[i] - (unsigned)ko;
        const unsigned val = (d < 8u) ? (hb[i] << ((d & 1u) * 16)) : 0u;
        const unsigned q = d >> 1;
        w0 |= (q == 0u) ? val : 0u;
        w1 |= (q == 1u) ? val : 0u;
        w2 |= (q == 2u) ? val : 0u;
        w3 |= (q == 3u) ? val : 0u;
    }
    union { unsigned u[4]; f16x8 v; } r;
    r.u[0] = w0; r.u[1] = w1; r.u[2] = w2; r.u[3] = w3;
    return r.v;
}

__device__ __forceinline__ f16x8 build_q_win(int kq, int ko)
{
    const unsigned d = (unsigned)(kq - ko);
    const unsigned val = (d < 8u) ? (0x3C00u << ((d & 1u) * 16)) : 0u;
    const unsigned q = d >> 1;
    union { unsigned u[4]; f16x8 v; } r;
    r.u[0] = (q == 0u) ? val : 0u;
    r.u[1] = (q == 1u) ? val : 0u;
    r.u[2] = (q == 2u) ? val : 0u;
    r.u[3] = (q == 3u) ? val : 0u;
    return r.v;
}

// LDS (58624 B). sOut f32[64][68]=17408 overlays [0, 34816) after sZ/sB1 die.
#define L_Z    0        // f32[64][65]  16640
#define L_B1   16640    // f16[64][168] 21504
#define L_W2   38144    // f16[64][72]   9216
#define L_H    47360    // f16[64][72]   9216
#define L_TOK  56576    // u32[64*6]     1536
#define L_ROW  58112    // uint4 slot reuses L_TOK region? no — separate:
#define L_QT   59136    // (see arena size below)
// arena: TOK 1536 + ROW(64*16=1024) + QT 256 + RB2 256 after L_H:
// L_TOK=56576, L_ROW=58112(1024), L_QT=59136(256), L_RB2=59392(256) -> 59648

__global__ __launch_bounds__(BT) void sm_main(
    const int* __restrict__ seqs, const int* __restrict__ qtok,
    const float* __restrict__ rb2, const char* __restrict__ wsc,
    float* __restrict__ out)
{
    __shared__ __align__(16) char smem[59648];
    float*    sZ   = (float*)(smem + L_Z);
    _Float16* sB1  = (_Float16*)(smem + L_B1);
    _Float16* sW2  = (_Float16*)(smem + L_W2);
    _Float16* sH   = (_Float16*)(smem + L_H);
    unsigned* sTok = (unsigned*)(smem + L_TOK);
    uint4*    sRow = (uint4*)(smem + 58112);
    int*      sQt  = (int*)(smem + 59136);
    float*    sRb2 = (float*)(smem + 59392);

    const int tid = threadIdx.x;
    const int base = blockIdx.x * ROWS;

    // ---- phase 0: stage everything (tokens first: deepest dependency) ----
    {
        const int4* sq = (const int4*)(seqs + (size_t)base * 24);   // 384 int4
        #pragma unroll
        for (int i = 0; i < 2; ++i) {
            const int g = tid + i * 256;
            if (g < 384) {
                const int4 w4 = sq[g];
                sTok[g] = (unsigned)w4.x | ((unsigned)w4.y << 8) |
                          ((unsigned)w4.z << 16) | ((unsigned)w4.w << 24);
            }
        }
        if (tid < 64) sQt[tid] = qtok[base + tid];
        if (tid >= 64 && tid < 128) sRb2[tid - 64] = rb2[tid - 64];
        const float* zsrc = (const float*)(wsc + WSB_Z);
        #pragma unroll
        for (int i = 0; i < 16; ++i) {
            const int e = tid + i * 256;
            sZ[(e >> 6) * 65 + (e & 63)] = zsrc[e];
        }
        const float4* b1s = (const float4*)(wsc + WSB_B1);
        float4* b1d = (float4*)sB1;
        for (int i = tid; i < 1344; i += 256) b1d[i] = b1s[i];
        const float4* w2s = (const float4*)(wsc + WSB_W2);
        float4* w2d = (float4*)sW2;
        for (int i = tid; i < 576; i += 256) w2d[i] = w2s[i];
    }
    __syncthreads();

    // ---- phase 1: quad-parallel scan (4 lanes per row, all 256 threads) ----
    {
        const int row = tid >> 2, sub = tid & 3;
        unsigned lo = sTok[row * 6 + 0];
        unsigned hi = sTok[row * 6 + 1];
        const unsigned char* tk = ((const unsigned char*)sTok) + row * 24;
        const int s0 = sub * 2, s1 = sub * 2 + 1;
        #pragma unroll
        for (int t = 8; t < TSTEPS; ++t) {
            const int c = tk[t];
            const float* zr = sZ + c * 65;
            const unsigned word = (sub < 2) ? lo : hi;
            const int sh = (sub & 1) * 16;
            const int b0 = (int)((word >> sh) & 63u);
            const int b1 = (int)((word >> (sh + 8)) & 63u);
            const float v0 = zr[b0], v1 = zr[b1];
            float bv; int bi;
            if (v1 > v0) { bv = v1; bi = s1; } else { bv = v0; bi = s0; }
            // quad argmax reduce, exact first-max semantics
            #pragma unroll
            for (int m = 1; m <= 2; m <<= 1) {
                const float ov = __shfl_xor(bv, m);
                const int   oi = __shfl_xor(bi, m);
                if (ov > bv || (ov == bv && oi < bi)) { bv = ov; bi = oi; }
            }
            const unsigned cb = (unsigned)c;
            if (bi < 4) { const int q = bi * 8;      lo = (lo & ~(255u << q)) | (cb << q); }
            else        { const int q = bi * 8 - 32; hi = (hi & ~(255u << q)) | (cb << q); }
        }
        if (sub == 0) {
            int t_[8] = { (int)(lo & 63), (int)((lo >> 8) & 63), (int)((lo >> 16) & 63), (int)(lo >> 24),
                          (int)(hi & 63), (int)((hi >> 8) & 63), (int)((hi >> 16) & 63), (int)(hi >> 24) };
            int tot[8] = {1, 1, 1, 1, 1, 1, 1, 1};
            #pragma unroll
            for (int i = 0; i < 8; ++i)
                #pragma unroll
                for (int j = i + 1; j < 8; ++j) {
                    const int eq = (t_[i] == t_[j]);
                    tot[i] += eq; tot[j] += eq;
                }
            unsigned tp = 0;
            #pragma unroll
            for (int i = 0; i < 8; ++i) tp |= (unsigned)tot[i] << (4 * i);
            sRow[row] = make_uint4(lo & 0x3F3F3F3Fu, hi & 0x3F3F3F3Fu, tp, (unsigned)sQt[row]);
        }
    }
    __syncthreads();

    // ---- phase 2: MFMA-1  h = A @ B1 (K=160), 4 waves cover 64 rows ----
    const int lane = tid & 63;
    const int w = tid >> 6;                 // 0..3
    const int c16 = lane & 15, g = lane >> 4;
    const int arow = w * 16 + c16;          // 0..63

    unsigned sl[8], hb[8];
    int kq;
    {
        const uint4 ri = sRow[arow];
        sl[0] = ri.x & 63u; sl[1] = (ri.x >> 8) & 63u;
        sl[2] = (ri.x >> 16) & 63u; sl[3] = ri.x >> 24;
        sl[4] = ri.y & 63u; sl[5] = (ri.y >> 8) & 63u;
        sl[6] = (ri.y >> 16) & 63u; sl[7] = ri.y >> 24;
        #pragma unroll
        for (int i = 0; i < 8; ++i) {
            const unsigned tot = (ri.z >> (4 * i)) & 15u;
            union { _Float16 h; unsigned short b; } cv;
            cv.h = (_Float16)(float)tot;
            hb[i] = (unsigned)cv.b;
        }
        kq = 64 + (int)ri.w;
    }

    f32x4 a0 = {0.f, 0.f, 0.f, 0.f}, a1 = a0, a2 = a0, a3 = a0;
    #pragma unroll
    for (int ks = 0; ks < 5; ++ks) {
        const int ko = ks * 32 + g * 8;
        const f16x8 af = (ks < 2) ? build_slot_win(sl, hb, ko) : build_q_win(kq, ko);
        const f16x8 b0 = *(const f16x8*)&sB1[(c16) * 168 + ko];
        const f16x8 b1 = *(const f16x8*)&sB1[(16 + c16) * 168 + ko];
        const f16x8 b2 = *(const f16x8*)&sB1[(32 + c16) * 168 + ko];
        const f16x8 b3 = *(const f16x8*)&sB1[(48 + c16) * 168 + ko];
        a0 = __builtin_amdgcn_mfma_f32_16x16x32_f16(af, b0, a0, 0, 0, 0);
        a1 = __builtin_amdgcn_mfma_f32_16x16x32_f16(af, b1, a1, 0, 0, 0);
        a2 = __builtin_amdgcn_mfma_f32_16x16x32_f16(af, b2, a2, 0, 0, 0);
        a3 = __builtin_amdgcn_mfma_f32_16x16x32_f16(af, b3, a3, 0, 0, 0);
    }
    {
        const int rbase = w * 16 + g * 4;
        #pragma unroll
        for (int j = 0; j < 4; ++j) {
            _Float16* hr = sH + (rbase + j) * 72;
            const float v0 = a0[j], v1 = a1[j], v2 = a2[j], v3 = a3[j];
            hr[c16]      = (_Float16)(v0 > 0.f ? v0 : 0.f);
            hr[16 + c16] = (_Float16)(v1 > 0.f ? v1 : 0.f);
            hr[32 + c16] = (_Float16)(v2 > 0.f ? v2 : 0.f);
            hr[48 + c16] = (_Float16)(v3 > 0.f ? v3 : 0.f);
        }
    }
    __syncthreads();

    // ---- phase 3: MFMA-2  logits = relu(h) @ W2t (K=64) ----
    f32x4 d0 = {0.f, 0.f, 0.f, 0.f}, d1 = d0, d2 = d0, d3 = d0;
    #pragma unroll
    for (int ks = 0; ks < 2; ++ks) {
        const int ko = ks * 32 + g * 8;
        const f16x8 af = *(const f16x8*)&sH[arow * 72 + ko];
        const f16x8 b0 = *(const f16x8*)&sW2[(c16) * 72 + ko];
        const f16x8 b1 = *(const f16x8*)&sW2[(16 + c16) * 72 + ko];
        const f16x8 b2 = *(const f16x8*)&sW2[(32 + c16) * 72 + ko];
        const f16x8 b3 = *(const f16x8*)&sW2[(48 + c16) * 72 + ko];
        d0 = __builtin_amdgcn_mfma_f32_16x16x32_f16(af, b0, d0, 0, 0, 0);
        d1 = __builtin_amdgcn_mfma_f32_16x16x32_f16(af, b1, d1, 0, 0, 0);
        d2 = __builtin_amdgcn_mfma_f32_16x16x32_f16(af, b2, d2, 0, 0, 0);
        d3 = __builtin_amdgcn_mfma_f32_16x16x32_f16(af, b3, d3, 0, 0, 0);
    }
    float* sOut = (float*)(void*)smem;      // overlays dead sZ/sB1
    {
        const int rbase = w * 16 + g * 4;
        #pragma unroll
        for (int j = 0; j < 4; ++j) {
            float* orow = sOut + (rbase + j) * 68;
            orow[c16]      = d0[j] * (1.f / 256.f) + sRb2[c16];
            orow[16 + c16] = d1[j] * (1.f / 256.f) + sRb2[16 + c16];
            orow[32 + c16] = d2[j] * (1.f / 256.f) + sRb2[32 + c16];
            orow[48 + c16] = d3[j] * (1.f / 256.f) + sRb2[48 + c16];
        }
    }
    __syncthreads();

    // ---- phase 4: coalesced store (64 rows × 16 f4 = 1024, 4/thread) ----
    #pragma unroll
    for (int r2 = 0; r2 < 4; ++r2) {
        const int idx = r2 * 256 + tid;
        const int row = idx >> 4, c4 = idx & 15;
        *(float4*)(out + (size_t)(base + row) * 64 + c4 * 4) =
            *(const float4*)&sOut[row * 68 + c4 * 4];
    }
}

extern "C" void kernel_launch(void* const* d_in, const int* in_sizes, int n_in,
                              void* d_out, int out_size, void* d_ws, size_t ws_size,
                              hipStream_t stream)
{
    const int* seqs    = (const int*)d_in[0];
    const int* qtok    = (const int*)d_in[1];
    const float* embed = (const float*)d_in[2];
    const float* gw1   = (const float*)d_in[3];
    const float* gb1   = (const float*)d_in[4];
    const float* gw2   = (const float*)d_in[5];
    const float* gb2   = (const float*)d_in[6];
    const float* rw1   = (const float*)d_in[7];
    const float* rb1   = (const float*)d_in[8];
    const float* rw2   = (const float*)d_in[9];
    const float* rb2   = (const float*)d_in[10];
    char* wsc  = (char*)d_ws;
    float* out = (float*)d_out;
    const int B = in_sizes[1];

    pre_all<<<82, 512, 0, stream>>>(embed, gw1, gb1, gw2, gb2, rw1, rb1, rw2, wsc);
    sm_main<<<B / ROWS, BT, 0, stream>>>(seqs, qtok, rb2, wsc, out);
}

// Round 16
// 19.125 us; speedup vs baseline: 1.4428x; 1.1879x over previous
//
#include <hip/hip_runtime.h>
#include <math.h>

typedef __attribute__((ext_vector_type(8))) _Float16 f16x8;
typedef __attribute__((ext_vector_type(4))) float f32x4;

#define TSTEPS 23
#define ROWS 128

// ws byte offsets
#define WSB_B1 0        // [64 n][168 k] f16 combined table *256 (21504 B)
#define WSB_W2 21504    // [64 n][72 k] f16 rw2 transposed (9216 B)
#define WSB_Z  30720    // [64][64] f32 RAW gate logit LUT (16384 B)

// ---- precompute: Z = tiled-v (bitwise chains) + f32 ILP combine ----
__global__ __launch_bounds__(512) void pre_all(
    const float* __restrict__ embed, const float* __restrict__ gw1,
    const float* __restrict__ gb1, const float* __restrict__ gw2,
    const float* __restrict__ gb2, const float* __restrict__ rw1,
    const float* __restrict__ rb1, const float* __restrict__ rw2,
    char* __restrict__ wsc)
{
    __shared__ float sE[66 * 64];     // Z: sEmbT[k][s] stride 65 (4160 used); B1: sEmb rows
    __shared__ float sW[128 * 64];    // gw1 [128][32] or rw1 [128][64]
    __shared__ float sV[64 * 33];
    __shared__ float sU[32];
    __shared__ float sG[65];          // gb1[0:32], gw2[32:64], gb2[64]
    __shared__ float sRb1[64];

    const int tid = threadIdx.x;
    const int blk = blockIdx.x;

    if (blk < 64) {
        // ---- Z row c = blk ----
        {
            // transpose-stage embed rows 0-63 into sEmbT[k*65+s]
            #pragma unroll
            for (int i = 0; i < 8; ++i) {
                const int e = tid + i * 512;             // 4096 elems
                const int s = e >> 6, k = e & 63;
                sE[k * 65 + s] = embed[s * 64 + k];
            }
            const float4* gs = (const float4*)gw1;       // [128][32] = 1024 f4
            float4* gd = (float4*)sW;
            for (int i = tid; i < 1024; i += 512) gd[i] = gs[i];
            if (tid < 32) { sG[tid] = gb1[tid]; sG[32 + tid] = gw2[tid]; }
            if (tid == 64) sG[64] = gb2[0];
        }
        __syncthreads();
        // v: 4s x 4j register tile, 128 threads. Per-output fmaf chain is
        // k-ascending — bitwise identical to all prior passing rounds.
        if (tid < 128) {
            const int s0 = (tid >> 3) * 4, j0 = (tid & 7) * 4;
            float acc[4][4];
            #pragma unroll
            for (int a = 0; a < 4; ++a)
                #pragma unroll
                for (int b = 0; b < 4; ++b) acc[a][b] = 0.f;
            #pragma unroll
            for (int k = 0; k < 64; ++k) {
                const float4 e4 = *(const float4*)&sE[k * 65 + s0];
                const float4 w4 = *(const float4*)&sW[(64 + k) * 32 + j0];
                acc[0][0] = fmaf(e4.x, w4.x, acc[0][0]); acc[0][1] = fmaf(e4.x, w4.y, acc[0][1]);
                acc[0][2] = fmaf(e4.x, w4.z, acc[0][2]); acc[0][3] = fmaf(e4.x, w4.w, acc[0][3]);
                acc[1][0] = fmaf(e4.y, w4.x, acc[1][0]); acc[1][1] = fmaf(e4.y, w4.y, acc[1][1]);
                acc[1][2] = fmaf(e4.y, w4.z, acc[1][2]); acc[1][3] = fmaf(e4.y, w4.w, acc[1][3]);
                acc[2][0] = fmaf(e4.z, w4.x, acc[2][0]); acc[2][1] = fmaf(e4.z, w4.y, acc[2][1]);
                acc[2][2] = fmaf(e4.z, w4.z, acc[2][2]); acc[2][3] = fmaf(e4.z, w4.w, acc[2][3]);
                acc[3][0] = fmaf(e4.w, w4.x, acc[3][0]); acc[3][1] = fmaf(e4.w, w4.y, acc[3][1]);
                acc[3][2] = fmaf(e4.w, w4.z, acc[3][2]); acc[3][3] = fmaf(e4.w, w4.w, acc[3][3]);
            }
            #pragma unroll
            for (int a = 0; a < 4; ++a)
                #pragma unroll
                for (int b = 0; b < 4; ++b)
                    sV[(s0 + a) * 33 + j0 + b] = acc[a][b];
        } else if (tid < 160) {
            // u: 32 outputs for c = blk (values & order identical: embed[blk][k])
            const int j = tid - 128;
            float acc = 0.f;
            #pragma unroll
            for (int k = 0; k < 64; ++k)
                acc = fmaf(sE[k * 65 + blk], sW[k * 32 + j], acc);
            sU[j] = acc;
        }
        __syncthreads();
        // f32 4-way ILP combine (numeric change this round; monotone-safe)
        if (tid < 64) {
            const int s = tid;
            float p0 = 0.f, p1 = 0.f, p2 = 0.f, p3 = 0.f;
            #pragma unroll
            for (int j = 0; j < 32; j += 4) {
                const float a0 = sU[j]     + sV[s * 33 + j]     + sG[j];
                const float a1 = sU[j + 1] + sV[s * 33 + j + 1] + sG[j + 1];
                const float a2 = sU[j + 2] + sV[s * 33 + j + 2] + sG[j + 2];
                const float a3 = sU[j + 3] + sV[s * 33 + j + 3] + sG[j + 3];
                if (a0 > 0.f) p0 = fmaf(a0, sG[32 + j],     p0);
                if (a1 > 0.f) p1 = fmaf(a1, sG[32 + j + 1], p1);
                if (a2 > 0.f) p2 = fmaf(a2, sG[32 + j + 2], p2);
                if (a3 > 0.f) p3 = fmaf(a3, sG[32 + j + 3], p3);
            }
            const float z = sG[64] + ((p0 + p1) + (p2 + p3));
            ((float*)(wsc + WSB_Z))[blk * 64 + s] = z;
        }
    } else if (blk < 81) {
        // ---- B1 combined table: verbatim R14 ----
        {
            const float4* es = (const float4*)embed;
            float4* ed = (float4*)sE;
            for (int i = tid; i < 1056; i += 512) ed[i] = es[i];
            const float4* rs = (const float4*)rw1;       // [128][64]
            float4* rd = (float4*)sW;
            for (int i = tid; i < 2048; i += 512) rd[i] = rs[i];
            if (tid < 64) sRb1[tid] = rb1[tid];
        }
        __syncthreads();
        const int e = (blk - 64) * 512 + tid;
        if (e < 8320) {
            const int n = e & 63, k = e >> 6;            // k < 130
            const int trow = (k < 64) ? k : (k - 64);
            const int ofs = (k < 64) ? 64 : 0;
            float4 er[16];
            const float4* erp = (const float4*)(sE + trow * 64);
            #pragma unroll
            for (int q = 0; q < 16; ++q) er[q] = erp[q];
            float acc = (k < 64) ? 0.f : sRb1[n];
            #pragma unroll
            for (int m = 0; m < 64; ++m)
                acc = fmaf(((const float*)er)[m], sW[(ofs + m) * 64 + n], acc);
            acc *= (k < 64) ? (0.125f * 256.f) : 256.f;
            ((_Float16*)(wsc + WSB_B1))[n * 168 + k] = (_Float16)acc;
        }
    } else {
        // ---- W2 transpose + B1 k-pads ----
        _Float16* w2t = (_Float16*)(wsc + WSB_W2);
        for (int e = tid; e < 4096; e += 512) {
            const int n = e & 63, j = e >> 6;
            w2t[n * 72 + j] = (_Float16)rw2[j * 64 + n];
        }
        _Float16* b1 = (_Float16*)(wsc + WSB_B1);
        for (int e = tid; e < 2432; e += 512) {          // k in [130,168)
            const int n = e / 38, k = 130 + (e - n * 38);
            b1[n * 168 + k] = (_Float16)0.f;
        }
    }
}

// ---- A-window builders (unchanged) ----
__device__ __forceinline__ f16x8 build_slot_win(const unsigned* s, const unsigned* hb, int ko)
{
    unsigned w0 = 0, w1 = 0, w2 = 0, w3 = 0;
    #pragma unroll
    for (int i = 0; i < 8; ++i) {
        const unsigned d = s[i] - (unsigned)ko;
        const unsigned val = (d < 8u) ? (hb[i] << ((d & 1u) * 16)) : 0u;
        const unsigned q = d >> 1;
        w0 |= (q == 0u) ? val : 0u;
        w1 |= (q == 1u) ? val : 0u;
        w2 |= (q == 2u) ? val : 0u;
        w3 |= (q == 3u) ? val : 0u;
    }
    union { unsigned u[4]; f16x8 v; } r;
    r.u[0] = w0; r.u[1] = w1; r.u[2] = w2; r.u[3] = w3;
    return r.v;
}

__device__ __forceinline__ f16x8 build_q_win(int kq, int ko)
{
    const unsigned d = (unsigned)(kq - ko);
    const unsigned val = (d < 8u) ? (0x3C00u << ((d & 1u) * 16)) : 0u;
    const unsigned q = d >> 1;
    union { unsigned u[4]; f16x8 v; } r;
    r.u[0] = (q == 0u) ? val : 0u;
    r.u[1] = (q == 1u) ? val : 0u;
    r.u[2] = (q == 2u) ? val : 0u;
    r.u[3] = (q == 3u) ? val : 0u;
    return r.v;
}

// LDS byte offsets (68096 B arena) — sOut f32[128][68] overlays [0, 34816)
#define L_Z    0        // f32[64][65] padded 16640
#define L_B1   16640    // f16[64][168] 21504
#define L_W2   38144    // f16[64][72]   9216
#define L_H    47360    // f16[128][72] 18432
#define L_ROW  65792    // uint4[128]    2048
#define L_RB2  67840    // f32[64]        256

__global__ __launch_bounds__(512) void sm_main(
    const int* __restrict__ seqs, const int* __restrict__ qtok,
    const float* __restrict__ rb2, const char* __restrict__ wsc,
    float* __restrict__ out)
{
    __shared__ __align__(16) char smem[68096];
    float*    sZ   = (float*)(smem + L_Z);
    _Float16* sB1  = (_Float16*)(smem + L_B1);
    _Float16* sW2  = (_Float16*)(smem + L_W2);
    _Float16* sH   = (_Float16*)(smem + L_H);
    uint4*    sRow = (uint4*)(smem + L_ROW);
    float*    sRb2 = (float*)(smem + L_RB2);

    const int tid = threadIdx.x;
    const int base = blockIdx.x * ROWS;

    unsigned pk[6];
    int qt = 0;
    if (tid < ROWS) {
        const int4* sq = (const int4*)(seqs + (size_t)(base + tid) * 24);
        #pragma unroll
        for (int i = 0; i < 6; ++i) {
            const int4 w4 = sq[i];
            pk[i] = (unsigned)w4.x | ((unsigned)w4.y << 8) |
                    ((unsigned)w4.z << 16) | ((unsigned)w4.w << 24);
        }
        qt = qtok[base + tid];
    }

    {
        const float* zsrc = (const float*)(wsc + WSB_Z);
        #pragma unroll
        for (int i = 0; i < 8; ++i) {
            const int e = tid + i * 512;
            sZ[(e >> 6) * 65 + (e & 63)] = zsrc[e];
        }
        if (tid < 64) sRb2[tid] = rb2[tid];
    }
    __syncthreads();

    if (tid < ROWS) {
        unsigned lo = pk[0], hi = pk[1];
        #pragma unroll
        for (int t = 8; t < TSTEPS; ++t) {
            const int c = (int)((pk[t >> 2] >> ((t & 3) * 8)) & 255u);
            const float* zr = sZ + c * 65;
            float b = zr[lo & 63]; int am = 0; float z;
            z = zr[(lo >> 8) & 63];  if (z > b) { b = z; am = 1; }
            z = zr[(lo >> 16) & 63]; if (z > b) { b = z; am = 2; }
            z = zr[lo >> 24];        if (z > b) { b = z; am = 3; }
            z = zr[hi & 63];         if (z > b) { b = z; am = 4; }
            z = zr[(hi >> 8) & 63];  if (z > b) { b = z; am = 5; }
            z = zr[(hi >> 16) & 63]; if (z > b) { b = z; am = 6; }
            z = zr[hi >> 24];        if (z > b) { b = z; am = 7; }
            const unsigned cb = (unsigned)c;
            if (am < 4) { const int sh = am * 8; lo = (lo & ~(255u << sh)) | (cb << sh); }
            else        { const int sh = am * 8 - 32; hi = (hi & ~(255u << sh)) | (cb << sh); }
        }
        int t_[8] = { (int)(lo & 63), (int)((lo >> 8) & 63), (int)((lo >> 16) & 63), (int)(lo >> 24),
                      (int)(hi & 63), (int)((hi >> 8) & 63), (int)((hi >> 16) & 63), (int)(hi >> 24) };
        int tot[8] = {1, 1, 1, 1, 1, 1, 1, 1};
        #pragma unroll
        for (int i = 0; i < 8; ++i)
            #pragma unroll
            for (int j = i + 1; j < 8; ++j) {
                const int eq = (t_[i] == t_[j]);
                tot[i] += eq; tot[j] += eq;
            }
        unsigned tp = 0;
        #pragma unroll
        for (int i = 0; i < 8; ++i) tp |= (unsigned)tot[i] << (4 * i);
        sRow[tid] = make_uint4(lo & 0x3F3F3F3Fu, hi & 0x3F3F3F3Fu, tp, (unsigned)qt);
    } else {
        const int t2 = tid - 128;
        const float4* b1s = (const float4*)(wsc + WSB_B1);
        float4* b1d = (float4*)sB1;
        for (int i = t2; i < 1344; i += 384) b1d[i] = b1s[i];
        const float4* w2s = (const float4*)(wsc + WSB_W2);
        float4* w2d = (float4*)sW2;
        for (int i = t2; i < 576; i += 384) w2d[i] = w2s[i];
    }
    __syncthreads();

    const int lane = tid & 63;
    const int w = tid >> 6;
    const int c16 = lane & 15, g = lane >> 4;
    const int arow = w * 16 + c16;

    unsigned sl[8], hb[8];
    int kq;
    {
        const uint4 ri = sRow[arow];
        sl[0] = ri.x & 63u; sl[1] = (ri.x >> 8) & 63u;
        sl[2] = (ri.x >> 16) & 63u; sl[3] = ri.x >> 24;
        sl[4] = ri.y & 63u; sl[5] = (ri.y >> 8) & 63u;
        sl[6] = (ri.y >> 16) & 63u; sl[7] = ri.y >> 24;
        #pragma unroll
        for (int i = 0; i < 8; ++i) {
            const unsigned tot = (ri.z >> (4 * i)) & 15u;
            union { _Float16 h; unsigned short b; } cv;
            cv.h = (_Float16)(float)tot;
            hb[i] = (unsigned)cv.b;
        }
        kq = 64 + (int)ri.w;
    }

    f32x4 a0 = {0.f, 0.f, 0.f, 0.f}, a1 = a0, a2 = a0, a3 = a0;
    #pragma unroll
    for (int ks = 0; ks < 5; ++ks) {
        const int ko = ks * 32 + g * 8;
        const f16x8 af = (ks < 2) ? build_slot_win(sl, hb, ko) : build_q_win(kq, ko);
        const f16x8 b0 = *(const f16x8*)&sB1[(c16) * 168 + ko];
        const f16x8 b1 = *(const f16x8*)&sB1[(16 + c16) * 168 + ko];
        const f16x8 b2 = *(const f16x8*)&sB1[(32 + c16) * 168 + ko];
        const f16x8 b3 = *(const f16x8*)&sB1[(48 + c16) * 168 + ko];
        a0 = __builtin_amdgcn_mfma_f32_16x16x32_f16(af, b0, a0, 0, 0, 0);
        a1 = __builtin_amdgcn_mfma_f32_16x16x32_f16(af, b1, a1, 0, 0, 0);
        a2 = __builtin_amdgcn_mfma_f32_16x16x32_f16(af, b2, a2, 0, 0, 0);
        a3 = __builtin_amdgcn_mfma_f32_16x16x32_f16(af, b3, a3, 0, 0, 0);
    }
    {
        const int rbase = w * 16 + g * 4;
        #pragma unroll
        for (int j = 0; j < 4; ++j) {
            _Float16* hr = sH + (rbase + j) * 72;
            const float v0 = a0[j], v1 = a1[j], v2 = a2[j], v3 = a3[j];
            hr[c16]      = (_Float16)(v0 > 0.f ? v0 : 0.f);
            hr[16 + c16] = (_Float16)(v1 > 0.f ? v1 : 0.f);
            hr[32 + c16] = (_Float16)(v2 > 0.f ? v2 : 0.f);
            hr[48 + c16] = (_Float16)(v3 > 0.f ? v3 : 0.f);
        }
    }
    __syncthreads();

    f32x4 d0 = {0.f, 0.f, 0.f, 0.f}, d1 = d0, d2 = d0, d3 = d0;
    #pragma unroll
    for (int ks = 0; ks < 2; ++ks) {
        const int ko = ks * 32 + g * 8;
        const f16x8 af = *(const f16x8*)&sH[arow * 72 + ko];
        const f16x8 b0 = *(const f16x8*)&sW2[(c16) * 72 + ko];
        const f16x8 b1 = *(const f16x8*)&sW2[(16 + c16) * 72 + ko];
        const f16x8 b2 = *(const f16x8*)&sW2[(32 + c16) * 72 + ko];
        const f16x8 b3 = *(const f16x8*)&sW2[(48 + c16) * 72 + ko];
        d0 = __builtin_amdgcn_mfma_f32_16x16x32_f16(af, b0, d0, 0, 0, 0);
        d1 = __builtin_amdgcn_mfma_f32_16x16x32_f16(af, b1, d1, 0, 0, 0);
        d2 = __builtin_amdgcn_mfma_f32_16x16x32_f16(af, b2, d2, 0, 0, 0);
        d3 = __builtin_amdgcn_mfma_f32_16x16x32_f16(af, b3, d3, 0, 0, 0);
    }
    float* sOut = (float*)(void*)smem;      // overlays dead sZ/sB1
    {
        const int rbase = w * 16 + g * 4;
        #pragma unroll
        for (int j = 0; j < 4; ++j) {
            float* orow = sOut + (rbase + j) * 68;
            orow[c16]      = d0[j] * (1.f / 256.f) + sRb2[c16];
            orow[16 + c16] = d1[j] * (1.f / 256.f) + sRb2[16 + c16];
            orow[32 + c16] = d2[j] * (1.f / 256.f) + sRb2[32 + c16];
            orow[48 + c16] = d3[j] * (1.f / 256.f) + sRb2[48 + c16];
        }
    }
    __syncthreads();

    #pragma unroll
    for (int r2 = 0; r2 < 4; ++r2) {
        const int idx = r2 * 512 + tid;
        const int row = idx >> 4, c4 = idx & 15;
        *(float4*)(out + (size_t)(base + row) * 64 + c4 * 4) =
            *(const float4*)&sOut[row * 68 + c4 * 4];
    }
}

extern "C" void kernel_launch(void* const* d_in, const int* in_sizes, int n_in,
                              void* d_out, int out_size, void* d_ws, size_t ws_size,
                              hipStream_t stream)
{
    const int* seqs    = (const int*)d_in[0];
    const int* qtok    = (const int*)d_in[1];
    const float* embed = (const float*)d_in[2];
    const float* gw1   = (const float*)d_in[3];
    const float* gb1   = (const float*)d_in[4];
    const float* gw2   = (const float*)d_in[5];
    const float* gb2   = (const float*)d_in[6];
    const float* rw1   = (const float*)d_in[7];
    const float* rb1   = (const float*)d_in[8];
    const float* rw2   = (const float*)d_in[9];
    const float* rb2   = (const float*)d_in[10];
    char* wsc  = (char*)d_ws;
    float* out = (float*)d_out;
    const int B = in_sizes[1];

    pre_all<<<82, 512, 0, stream>>>(embed, gw1, gb1, gw2, gb2, rw1, rb1, rw2, wsc);
    sm_main<<<B / ROWS, 512, 0, stream>>>(seqs, qtok, rb2, wsc, out);
}